// Round 16
// baseline (6978.001 us; speedup 1.0000x reference)
//
#include <hip/hip_runtime.h>
#include <math.h>

// RNN with short-term plasticity: persistent kernel, 16 independent
// groups of 32 WGs (batch-partitioned, GBATCH=2), per-group barrier.
//
// Round 16: round-15's kernel A launched as a PLAIN REGULAR launch.
// Round 14 failed because hipLaunchCooperativeKernel rejects >256 blocks;
// round 15's occupancy guard failed spuriously (void* kernel-symbol query
// in a shared library) and fell back. The launch needs no cooperative
// support: hand-rolled per-group sync only needs co-residency, which is
// guaranteed by construction (launch_bounds(512,2) caps VGPR at 128 --
// observed 80-124 on every (512,2) build -- and LDS is 11.3 KB, so 2
// blocks/CU fit => all 512 blocks resident). Safety net: groups are
// CONTIGUOUS 32-block ranges, so even at occupancy 1 whole groups become
// resident, complete, and free CUs (serialization, never deadlock).
//
// Why GBATCH=2/16 groups beats round 11 (GBATCH=4/8 groups): wall time =
// 1000 x per-group serial chain (flag RTT + A RTT + compute). Halving
// per-group batches halves the compute+staging term of the chain; the
// latency terms are unchanged. Co-residency itself hides nothing.
//
#define NH 1024
#define NB 32
#define NI 8
#define NO 8
#define TSTEPS 1000

#define NWG 512
#define BLK 512
#define NG 16         // independent groups
#define NM 32         // members per group
#define GB 2          // batches per group

#define OFF_Z 0
#define OFF_H (NB * TSTEPS * NO)            // 256000
#define OFF_R (OFF_H + NB * TSTEPS * NH)    // 33024000
#define OFF_U (OFF_R + NB * TSTEPS * NH)    // 65792000

// d_ws float offsets: slots 512x128B = 64 KB, then A, then ZP
#define WS_A  16384                             // A[2][NG][NH][GB]
#define WS_ZP (WS_A + 2 * NG * NH * GB)         // ZP[2][NG][GB][NO][NM]

typedef unsigned long long u64;

__device__ __forceinline__ float2 aload2(const float* p) {
    u64 v = __hip_atomic_load((const u64*)p, __ATOMIC_RELAXED,
                              __HIP_MEMORY_SCOPE_AGENT);
    return __builtin_bit_cast(float2, v);
}
__device__ __forceinline__ float aload1(const float* p) {
    return __hip_atomic_load(p, __ATOMIC_RELAXED, __HIP_MEMORY_SCOPE_AGENT);
}
__device__ __forceinline__ void astore(float* p, float v) {
    __hip_atomic_store(p, v, __ATOMIC_RELAXED, __HIP_MEMORY_SCOPE_AGENT);
}

// Per-group barrier: member m stamps slot [G][m] (128B-strided; round 7
// proved packed slots serialize); lanes<NM of wave 0 poll. Release
// ordering: leading __syncthreads drains vmcnt in every wave (agent
// stores ack'd at the coherence point) before thread 0 stamps.
__device__ __forceinline__ void groupbar(unsigned* slot, int G, int m,
                                         unsigned stamp) {
    __syncthreads();
    if (threadIdx.x == 0)
        __hip_atomic_store(&slot[(G * NM + m) * 32], stamp,
                           __ATOMIC_RELAXED, __HIP_MEMORY_SCOPE_AGENT);
    if (threadIdx.x < NM) {
        while (__hip_atomic_load(&slot[(G * NM + threadIdx.x) * 32],
                                 __ATOMIC_RELAXED, __HIP_MEMORY_SCOPE_AGENT)
               < stamp)
            __builtin_amdgcn_s_sleep(1);
    }
    __syncthreads();
}

__global__ __launch_bounds__(BLK, 2) void rnn_stp_kernel(
    const float* __restrict__ x,     // [32][1000][8]
    const float* __restrict__ h0,    // [32][1024]
    const float* __restrict__ r0,    // [32][1024]
    const float* __restrict__ u0,    // [32][1024]
    const float* __restrict__ prel,  // [1024]
    const float* __restrict__ scal,  // [1024]
    const float* __restrict__ Wih,   // [1024][8]
    const float* __restrict__ Whh,   // [1024][1024]
    const float* __restrict__ Wmask, // [1024][1024]
    const float* __restrict__ Whz,   // [8][1024]
    float* __restrict__ out,
    float* __restrict__ ws)
{
    const int tid = threadIdx.x;
    const int g   = blockIdx.x;

    // Contiguous groups: G = g>>5 (deadlock-safety under any dispatch).
    const int G = g >> 5;
    const int m = g & 31;

    unsigned* slot = (unsigned*)ws;
    float* Abuf = ws + WS_A;    // [2][NG][NH][GB]
    float* ZP   = ws + WS_ZP;   // [2][NG][GB][NO][NM]

    const int ib = 32 * m;      // first of 32 owned neurons

    __shared__ float2 atile[NH + NM];          // padded: row j -> j + (j>>5)
    __shared__ float  red[8 * 16 * 5];
    __shared__ float  hbuf[GB][NM];

    const int lane = tid & 63, wid = tid >> 6;

    // ---- GEMM roles: ks = tid>>4 (j in [32ks,+32)), il = tid&15 ----
    const int ks = tid >> 4;
    const int il = tid & 15;

    // Masked weights (fully static indexing -> register-resident, rule #20)
    float w[2][32];
    #pragma unroll
    for (int nn = 0; nn < 2; ++nn) {
        const int row = 32 * m + il + 16 * nn;
        const float* wp = Whh   + row * NH + 32 * ks;
        const float* mp = Wmask + row * NH + 32 * ks;
        #pragma unroll
        for (int jj = 0; jj < 32; ++jj) w[nn][jj] = wp[jj] * mp[jj];
    }

    // ---- owner role: tid<64: local batch ob = tid>>5, neuron on = tid&31 ----
    const bool own = tid < 64;
    const int ob = tid >> 5;
    const int on = tid & 31;
    const int bglob = G * GB + ob;
    const int oi = ib + on;
    float h = 0.f, r = 0.f, u = 0.f, htr = 0.f, p = 0.f, sc = 0.f;
    float wih[8];
    if (own) {
        h  = h0[bglob * NH + oi];
        r  = r0[bglob * NH + oi];
        u  = u0[bglob * NH + oi];
        p  = prel[oi];
        sc = scal[oi];
        #pragma unroll
        for (int k = 0; k < 8; ++k) wih[k] = Wih[oi * NI + k];
        htr = tanhf(h);
        astore(&Abuf[G * (NH * GB) + oi * GB + ob], r * sc * htr);
    }

    // ---- z-partial consts (waves 0..1): o = lane>>3, ns = lane&7 ----
    float wzv[4];
    #pragma unroll
    for (int k = 0; k < 4; ++k)
        wzv[k] = Whz[(lane >> 3) * NH + ib + (lane & 7) + 8 * k];
    // ---- z-finalize consts (wave 4, members m<16): (bf, of) ----
    const int bf = (m >> 3) & 1, of = m & 7;

    unsigned stamp = 1;
    groupbar(slot, G, m, stamp); ++stamp;

    for (int t = 0; t < TSTEPS; ++t) {
        const int par = t & 1;

        // ---- stage A[par][G] (8 KB): rows 2tid, 2tid+1 (float2 each) ----
        const float* Ag = Abuf + par * (NG * NH * GB) + G * (NH * GB);
        {
            float2 s0 = aload2(Ag + (2 * tid) * 2);
            float2 s1 = aload2(Ag + (2 * tid + 1) * 2);
            const int r0i = 2 * tid;
            atile[r0i + (r0i >> 5)]     = s0;
            atile[r0i + 1 + (r0i >> 5)] = s1;
        }

        // ---- x prefetch for owners (cached, latency-tolerant) ----
        float4 xa = make_float4(0.f, 0.f, 0.f, 0.f), xb = xa;
        if (own) {
            const float4* xp = (const float4*)(x + (bglob * TSTEPS + t) * NI);
            xa = xp[0];
            xb = xp[1];
        }
        __syncthreads();

        // ---- GEMM: 32 j x 2 rows x 2 b; FULL unroll, static indices ----
        float acc[2][2] = {{0.f, 0.f}, {0.f, 0.f}};
        {
            const float2* at2 = atile + 33 * ks;
            #pragma unroll
            for (int jj = 0; jj < 32; ++jj) {
                float2 a = at2[jj];
                const float w0 = w[0][jj], w1 = w[1][jj];
                acc[0][0] = fmaf(a.x, w0, acc[0][0]);
                acc[0][1] = fmaf(a.y, w0, acc[0][1]);
                acc[1][0] = fmaf(a.x, w1, acc[1][0]);
                acc[1][1] = fmaf(a.y, w1, acc[1][1]);
            }
        }

        // ---- butterfly over ks low bits (lane bits 4,5) ----
        #pragma unroll
        for (int mm = 16; mm <= 32; mm <<= 1) {
            #pragma unroll
            for (int nn = 0; nn < 2; ++nn) {
                #pragma unroll
                for (int q = 0; q < 2; ++q)
                    acc[nn][q] += __shfl_xor(acc[nn][q], mm, 64);
            }
        }
        if (lane < 16) {
            float* rp = red + (wid * 16 + lane) * 5;
            rp[0] = acc[0][0]; rp[1] = acc[0][1];
            rp[2] = acc[1][0]; rp[3] = acc[1][1];
        }
        __syncthreads();

        // ---- owner: combine 8 wave partials, update state, write out ----
        if (own) {
            float rec = 0.f;
            #pragma unroll
            for (int wv = 0; wv < 8; ++wv)
                rec += red[(wv * 16 + (on & 15)) * 5 + (on >> 4) * 2 + ob];

            float xv = fmaf(xa.x, wih[0], fmaf(xa.y, wih[1],
                       fmaf(xa.z, wih[2], xa.w * wih[3])));
            xv = fmaf(xb.x, wih[4], fmaf(xb.y, wih[5],
                 fmaf(xb.z, wih[6], fmaf(xb.w, wih[7], xv))));

            float drive = 0.5f * (1.0f + htr);
            float rn = r + ((p - r) / 0.2f - 10.0f * r * drive) * 0.001f;
            float un = u + ((p - u) / 1.5f + 10.0f * (1.0f - u) * drive) * 0.001f;
            float hn = h + ((-h + xv + rec) / 0.01f) * 0.001f;
            float htn = tanhf(hn);

            out[OFF_H + (bglob * TSTEPS + t) * NH + oi] = hn;
            out[OFF_R + (bglob * TSTEPS + t) * NH + oi] = rn;
            out[OFF_U + (bglob * TSTEPS + t) * NH + oi] = un;

            astore(&Abuf[(par ^ 1) * (NG * NH * GB) + G * (NH * GB)
                         + oi * GB + ob], rn * sc * htn);
            hbuf[ob][on] = htn;

            h = hn; r = rn; u = un; htr = htn;
        }
        // ---- z finalize for step t-1: wave 4, members m<16 (parallel) ----
        if (t >= 1 && wid == 4 && m < 16 && lane < NM) {
            float v = aload1(ZP + (par ^ 1) * (NG * GB * NO * NM)
                             + G * (GB * NO * NM)
                             + bf * (NO * NM) + of * NM + lane);
            v += __shfl_xor(v, 1, 64);
            v += __shfl_xor(v, 2, 64);
            v += __shfl_xor(v, 4, 64);
            v += __shfl_xor(v, 8, 64);
            v += __shfl_xor(v, 16, 64);
            if (lane == 0)
                out[OFF_Z + ((G * GB + bf) * TSTEPS + (t - 1)) * NO + of] = v;
        }
        __syncthreads();   // hbuf visible to z-partial waves

        // ---- z partials for step t: waves 0..1 (b = wid) ----
        if (wid < GB) {
            const int o = lane >> 3, ns = lane & 7;
            float zp = 0.f;
            #pragma unroll
            for (int k = 0; k < 4; ++k)
                zp = fmaf(hbuf[wid][ns + 8 * k], wzv[k], zp);
            zp += __shfl_xor(zp, 1, 64);
            zp += __shfl_xor(zp, 2, 64);
            zp += __shfl_xor(zp, 4, 64);
            if (ns == 0)
                astore(&ZP[par * (NG * GB * NO * NM)
                           + G * (GB * NO * NM)
                           + wid * (NO * NM) + o * NM + m], zp);
        }

        groupbar(slot, G, m, stamp); ++stamp;
    }

    // ---- epilogue: finalize z[999] (partials in ZP[1]) ----
    if (wid == 4 && m < 16) {
        float v = 0.f;
        if (lane < NM)
            v = aload1(ZP + 1 * (NG * GB * NO * NM)
                       + G * (GB * NO * NM)
                       + bf * (NO * NM) + of * NM + lane);
        v += __shfl_xor(v, 1, 64);
        v += __shfl_xor(v, 2, 64);
        v += __shfl_xor(v, 4, 64);
        v += __shfl_xor(v, 8, 64);
        v += __shfl_xor(v, 16, 64);
        if (lane == 0)
            out[OFF_Z + ((G * GB + bf) * TSTEPS + 999) * NO + of] = v;
    }
}

extern "C" void kernel_launch(void* const* d_in, const int* in_sizes, int n_in,
                              void* d_out, int out_size, void* d_ws, size_t ws_size,
                              hipStream_t stream) {
    const float* x     = (const float*)d_in[0];
    const float* h0    = (const float*)d_in[1];
    const float* r0    = (const float*)d_in[2];
    const float* u0    = (const float*)d_in[3];
    const float* prel  = (const float*)d_in[4];
    const float* scal  = (const float*)d_in[5];
    const float* Wih   = (const float*)d_in[6];
    const float* Whh   = (const float*)d_in[7];
    const float* Wmask = (const float*)d_in[8];
    const float* Whz   = (const float*)d_in[9];
    float* out = (float*)d_out;
    float* ws  = (float*)d_ws;

    // Zero the 512 barrier slots (128B apart) each launch.
    hipMemsetAsync(d_ws, 0, NWG * 128, stream);

    // Plain regular launch: 512 blocks x 512 threads, 2 blocks/CU.
    rnn_stp_kernel<<<dim3(NWG), dim3(BLK), 0, stream>>>(
        x, h0, r0, u0, prel, scal, Wih, Whh, Wmask, Whz, out, ws);
}